// Round 9
// baseline (249.723 us; speedup 1.0000x reference)
//
#include <hip/hip_runtime.h>

// LBP for semantic dependency parsing — label-difference form, all 3
// iterations fused, message chain computed in u-SPACE (u = 2^D):
//
//   F[b,i,j,k] = 2^(log2e*s) = e^s                (only use of the scores)
//   u_1 = (p1 + F)*r1,          p1 = 2^(-q0[i]), r1 = 1/(1+p1)
//   u_t = (p + F)/(1 + p),      p = u_{t-1} * 2^(-q_{t-1}[i])
//   q_t[k] = q0[k] + mask[k] * sum_i log2(u_s*u_c*u_g)[i,k]
//                               * mask[i]*(i!=j)*(i!=k)
//   out[b,k,j] = 1/(1+2^(-q_3[k]))
//
// vs the log-space chain (rounds 6-8: 13 trans/score) this needs only
// ~5 trans/score: 1 exp2 (stage) + 1 rcp per score per later pass +
// 1 log2 per 3-tensor triple. Block (b,j) closes the whole recursion for
// column j; F is cached in PACKED FP16 registers (48 VGPRs, precision
// proven in r7/r8: absmax 0.0078), chain recomputed from q-history.
// amdgpu_waves_per_eu(2,4) grants the allocator a 256-VGPR budget so the
// payload is NOT shed to scratch (r4-r8 showed the default heuristic
// spills any payload beyond ~50 VGPRs).

#define TS 128

typedef float    f4v __attribute__((ext_vector_type(4)));
typedef _Float16 h4v __attribute__((ext_vector_type(4)));

constexpr float LOG2E = 1.4426950408889634f;

__device__ __forceinline__ float rcpf(float x)   { return __builtin_amdgcn_rcpf(x); }
__device__ __forceinline__ float clampe(float e) { return fminf(fmaxf(e, -126.0f), 60.0f); }

// ---- mask format probe: f[0]!=0 -> byte mask, f[1]!=0 -> float32, else int32
__global__ void flags_init(int* __restrict__ f) { f[0] = 0; f[1] = 0; }

__global__ void mask_detect(const unsigned char* __restrict__ m, int n, int* __restrict__ f) {
    int v1 = 0, v23 = 0;
    for (int i = blockIdx.x * blockDim.x + threadIdx.x; i < n; i += gridDim.x * blockDim.x) {
        const unsigned char b = m[i];           // first n bytes: in-bounds for all layouts
        const int r = i & 3;
        if (r == 1) v1 |= b;
        if (r >= 2) v23 |= b;
    }
    const int lane = threadIdx.x & 63;
    if (__any(v1)  && lane == 0) atomicOr(&f[0], 1);
    if (__any(v23) && lane == 0) atomicOr(&f[1], 1);
}

// u after DEPTH message updates (q-history via p1,r1,g1,g2)
template <int DEPTH>
__device__ __forceinline__ float uchain(float F, float p1, float r1, float g1, float g2) {
    float u = (p1 + F) * r1;
    if constexpr (DEPTH >= 2) { const float p = u * g1; u = (p + F) * rcpf(1.0f + p); }
    if constexpr (DEPTH >= 3) { const float p = u * g2; u = (p + F) * rcpf(1.0f + p); }
    return u;
}

__global__ __launch_bounds__(512)
__attribute__((amdgpu_waves_per_eu(2, 4)))
void lbp_fused(const float* __restrict__ s_edge,
               const f4v* __restrict__ sib4,
               const f4v* __restrict__ cop4,
               const f4v* __restrict__ grd4,
               const void* __restrict__ mask,
               const int* __restrict__ flags,
               float* __restrict__ outp)
{
    __shared__ float q0s[TS], p1s[TS], r1s[TS], g1s[TS], g2s[TS];
    __shared__ f4v red4[16 * 32];       // 8 KB: [row-group][k-quad]
    __shared__ unsigned char mrow[TS];

    const int bj = blockIdx.x;
    const int b  = bj >> 7;
    const int j  = bj & (TS - 1);
    const int t  = threadIdx.x;
    const int kq = t & 31;              // k = 4*kq .. 4*kq+3
    const int rg = t >> 5;              // row group 0..15 (8 rows each)
    const int i0 = rg * 8;
    const int k0 = kq * 4;

    // ---- per-column prologue ----
    if (t < TS) {
        const int i = t;
        const int idx = (b * TS + i) * TS + j;
        const float q0 = LOG2E * s_edge[idx];
        q0s[i] = q0;
        const int f1 = flags[0], f23 = flags[1];
        unsigned char mv;
        if (f1)       mv = ((const unsigned char*)mask)[idx] != 0;
        else if (f23) mv = ((const float*)mask)[idx] != 0.0f;
        else          mv = ((const int*)mask)[idx]   != 0;
        mrow[i] = mv;
        const float p1 = exp2f(clampe(-q0));
        p1s[i] = p1;
        r1s[i] = rcpf(1.0f + p1);
    }
    __syncthreads();

    const size_t colBase4 = (size_t)b * (TS * TS * TS / 4) + (size_t)j * (TS / 4) + kq;

    // ---- stage + pass 1: scores -> F (fp16 regs); u1 needs NO trans/score ----
    h4v Fsh[8], Fch[8], Fgh[8];
    f4v acc = {0.0f, 0.0f, 0.0f, 0.0f};
    #pragma unroll 2
    for (int r = 0; r < 8; ++r) {
        const int i = i0 + r;
        const size_t off = colBase4 + (size_t)i * (TS * TS / 4);
        const f4v vs = sib4[off];
        const f4v vc = cop4[off];
        const f4v vg = grd4[off];
        f4v fs, fc, fg;
        #pragma unroll
        for (int c = 0; c < 4; ++c) {
            fs[c] = exp2f(LOG2E * vs[c]);
            fc[c] = exp2f(LOG2E * vc[c]);
            fg[c] = exp2f(LOG2E * vg[c]);
        }
        Fsh[r] = __builtin_convertvector(fs, h4v);
        Fch[r] = __builtin_convertvector(fc, h4v);
        Fgh[r] = __builtin_convertvector(fg, h4v);
        const bool live = (mrow[i] != 0) && (i != j);
        const float p1 = p1s[i], r1 = r1s[i];
        #pragma unroll
        for (int c = 0; c < 4; ++c) {
            const float us = (p1 + fs[c]) * r1;
            const float uc = (p1 + fc[c]) * r1;
            const float ug = (p1 + fg[c]) * r1;
            const float l  = __log2f(us * uc * ug);
            if (live && (i != k0 + c)) acc[c] += l;
        }
    }
    red4[t] = acc;
    __syncthreads();
    if (t < TS) {
        const float* red = (const float*)red4;
        float tot = 0.0f;
        #pragma unroll
        for (int g = 0; g < 16; ++g) tot += red[g * TS + t];
        const float q1 = q0s[t] + (mrow[t] ? tot : 0.0f);
        g1s[t] = exp2f(clampe(-q1));
    }
    __syncthreads();

    // ---- pass 2: u2 via 1 rcp/score ----
    acc[0] = acc[1] = acc[2] = acc[3] = 0.0f;
    #pragma unroll 2
    for (int r = 0; r < 8; ++r) {
        const int i = i0 + r;
        const bool live = (mrow[i] != 0) && (i != j);
        if (live) {
            const float p1 = p1s[i], r1 = r1s[i], g1 = g1s[i];
            const f4v fs = __builtin_convertvector(Fsh[r], f4v);
            const f4v fc = __builtin_convertvector(Fch[r], f4v);
            const f4v fg = __builtin_convertvector(Fgh[r], f4v);
            #pragma unroll
            for (int c = 0; c < 4; ++c) {
                const float us = uchain<2>(fs[c], p1, r1, g1, 0.0f);
                const float uc = uchain<2>(fc[c], p1, r1, g1, 0.0f);
                const float ug = uchain<2>(fg[c], p1, r1, g1, 0.0f);
                const float l  = __log2f(us * uc * ug);
                if (i != k0 + c) acc[c] += l;
            }
        }
    }
    red4[t] = acc;
    __syncthreads();
    if (t < TS) {
        const float* red = (const float*)red4;
        float tot = 0.0f;
        #pragma unroll
        for (int g = 0; g < 16; ++g) tot += red[g * TS + t];
        const float q2 = q0s[t] + (mrow[t] ? tot : 0.0f);
        g2s[t] = exp2f(clampe(-q2));
    }
    __syncthreads();

    // ---- pass 3: u3 via 2 rcp/score ----
    acc[0] = acc[1] = acc[2] = acc[3] = 0.0f;
    #pragma unroll 2
    for (int r = 0; r < 8; ++r) {
        const int i = i0 + r;
        const bool live = (mrow[i] != 0) && (i != j);
        if (live) {
            const float p1 = p1s[i], r1 = r1s[i], g1 = g1s[i], g2 = g2s[i];
            const f4v fs = __builtin_convertvector(Fsh[r], f4v);
            const f4v fc = __builtin_convertvector(Fch[r], f4v);
            const f4v fg = __builtin_convertvector(Fgh[r], f4v);
            #pragma unroll
            for (int c = 0; c < 4; ++c) {
                const float us = uchain<3>(fs[c], p1, r1, g1, g2);
                const float uc = uchain<3>(fc[c], p1, r1, g1, g2);
                const float ug = uchain<3>(fg[c], p1, r1, g1, g2);
                const float l  = __log2f(us * uc * ug);
                if (i != k0 + c) acc[c] += l;
            }
        }
    }
    red4[t] = acc;
    __syncthreads();
    if (t < TS) {
        const float* red = (const float*)red4;
        float tot = 0.0f;
        #pragma unroll
        for (int g = 0; g < 16; ++g) tot += red[g * TS + t];
        const float q3 = q0s[t] + (mrow[t] ? tot : 0.0f);
        outp[(b * TS + t) * TS + j] = 1.0f / (1.0f + exp2f(-q3));
    }
}

extern "C" void kernel_launch(void* const* d_in, const int* in_sizes, int n_in,
                              void* d_out, int out_size, void* d_ws, size_t ws_size,
                              hipStream_t stream) {
    const float* s_edge = (const float*)d_in[0];
    const f4v*   sib4   = (const f4v*)d_in[1];
    const f4v*   cop4   = (const f4v*)d_in[2];
    const f4v*   grd4   = (const f4v*)d_in[3];
    const void*  mask   = d_in[4];
    float* out = (float*)d_out;

    const int Bn = in_sizes[0] / (TS * TS);   // batch
    const int nMask = in_sizes[4];            // B*S*S elements

    int* flags = (int*)d_ws;

    flags_init<<<1, 1, 0, stream>>>(flags);
    mask_detect<<<64, 256, 0, stream>>>((const unsigned char*)mask, nMask, flags);
    lbp_fused<<<Bn * TS, 512, 0, stream>>>(s_edge, sib4, cop4, grd4, mask, flags, out);
}

// Round 10
// 85.533 us; speedup vs baseline: 2.9196x; 2.9196x over previous
//
#include <hip/hip_runtime.h>

// LBP for semantic dependency parsing — label-difference form, all 3
// iterations fused, u-SPACE chain (u = 2^D), fp16 F payload, tuned for
// OCCUPANCY (r9 post-mortem: duration tracks resident waves, not op count).
//
//   F[b,i,j,k] = 2^(log2e*s) = e^s                (only use of the scores)
//   u_1 = (p1 + F)*r1,          p1 = 2^(-q0[i]), r1 = 1/(1+p1)
//   u_t = (p + F)/(1 + p),      p = u_{t-1} * 2^(-q_{t-1}[i])
//   q_t[k] = q0[k] + mask[k] * sum_i log2(u_s*u_c*u_g)[i,k]
//                               * mask[i]*(i!=j)*(i!=k)
//   out[b,k,j] = 1/(1+2^(-q_3[k]))
//
// Block (b,j) closes the whole recursion for column j. Geometry: 1024 thr,
// thread = (kq = t&31 -> 4 k's, rg = t>>5 -> rows rg+32r, r=0..3).
// Payload = 12 x h4v = 24 VGPRs (fp16 F, precision proven r7-r9:
// absmax 0.0078 vs threshold 0.02). Passes 2-3 are pure register math.
// All 12 dwordx4 loads issued before compute for max MLP.

#define TS 128

typedef float    f4v __attribute__((ext_vector_type(4)));
typedef _Float16 h4v __attribute__((ext_vector_type(4)));

constexpr float LOG2E = 1.4426950408889634f;

__device__ __forceinline__ float rcpf(float x)   { return __builtin_amdgcn_rcpf(x); }
__device__ __forceinline__ float clampe(float e) { return fminf(fmaxf(e, -126.0f), 60.0f); }

// ---- mask format probe: f[0]!=0 -> byte mask, f[1]!=0 -> float32, else int32
__global__ void flags_init(int* __restrict__ f) { f[0] = 0; f[1] = 0; }

__global__ void mask_detect(const unsigned char* __restrict__ m, int n, int* __restrict__ f) {
    int v1 = 0, v23 = 0;
    for (int i = blockIdx.x * blockDim.x + threadIdx.x; i < n; i += gridDim.x * blockDim.x) {
        const unsigned char b = m[i];           // first n bytes: in-bounds for all layouts
        const int r = i & 3;
        if (r == 1) v1 |= b;
        if (r >= 2) v23 |= b;
    }
    const int lane = threadIdx.x & 63;
    if (__any(v1)  && lane == 0) atomicOr(&f[0], 1);
    if (__any(v23) && lane == 0) atomicOr(&f[1], 1);
}

__global__ __launch_bounds__(1024)
void lbp_fused(const float* __restrict__ s_edge,
               const f4v* __restrict__ sib4,
               const f4v* __restrict__ cop4,
               const f4v* __restrict__ grd4,
               const void* __restrict__ mask,
               const int* __restrict__ flags,
               float* __restrict__ outp)
{
    __shared__ float q0s[TS], p1s[TS], r1s[TS], g1s[TS], g2s[TS];
    __shared__ f4v red4[16 * 32];       // 8 KB: [wave][k-quad]
    __shared__ unsigned char mrow[TS];

    const int bj = blockIdx.x;
    const int b  = bj >> 7;
    const int j  = bj & (TS - 1);
    const int t  = threadIdx.x;
    const int kq = t & 31;              // k = 4*kq .. 4*kq+3
    const int rg = t >> 5;              // 0..31: rows rg, rg+32, rg+64, rg+96
    const int k0 = kq * 4;
    const int lane = t & 63;
    const int wv = t >> 6;              // wave 0..15

    // ---- per-column prologue ----
    if (t < TS) {
        const int i = t;
        const int idx = (b * TS + i) * TS + j;
        const float q0 = LOG2E * s_edge[idx];
        q0s[i] = q0;
        const int f1 = flags[0], f23 = flags[1];
        unsigned char mv;
        if (f1)       mv = ((const unsigned char*)mask)[idx] != 0;
        else if (f23) mv = ((const float*)mask)[idx] != 0.0f;
        else          mv = ((const int*)mask)[idx]   != 0;
        mrow[i] = mv;
        const float p1 = exp2f(clampe(-q0));
        p1s[i] = p1;
        r1s[i] = rcpf(1.0f + p1);
    }
    __syncthreads();

    const size_t base4 = (size_t)b * (TS * TS * TS / 4) + (size_t)j * (TS / 4) + kq;

    // ---- stage: issue all 12 dwordx4 loads up front (max MLP) ----
    f4v vs[4], vc[4], vg[4];
    #pragma unroll
    for (int r = 0; r < 4; ++r) {
        const size_t off = base4 + (size_t)(rg + 32 * r) * (TS * TS / 4);
        vs[r] = sib4[off];
        vc[r] = cop4[off];
        vg[r] = grd4[off];
    }

    // ---- pass 1: F = e^s (pack to fp16), u1 = (p1+F)*r1, no extra trans ----
    h4v Fs[4], Fc[4], Fg[4];
    f4v acc = {0.0f, 0.0f, 0.0f, 0.0f};
    #pragma unroll
    for (int r = 0; r < 4; ++r) {
        const int i = rg + 32 * r;
        f4v fs, fc, fg;
        #pragma unroll
        for (int c = 0; c < 4; ++c) {
            fs[c] = exp2f(LOG2E * vs[r][c]);
            fc[c] = exp2f(LOG2E * vc[r][c]);
            fg[c] = exp2f(LOG2E * vg[r][c]);
        }
        Fs[r] = __builtin_convertvector(fs, h4v);
        Fc[r] = __builtin_convertvector(fc, h4v);
        Fg[r] = __builtin_convertvector(fg, h4v);
        const bool live = (mrow[i] != 0) && (i != j);
        const float p1 = p1s[i], r1 = r1s[i];
        #pragma unroll
        for (int c = 0; c < 4; ++c) {
            const float us = (p1 + fs[c]) * r1;
            const float uc = (p1 + fc[c]) * r1;
            const float ug = (p1 + fg[c]) * r1;
            const float l  = __log2f(us * uc * ug);
            if (live && (i != k0 + c)) acc[c] += l;
        }
    }

    // reduce -> q1 -> g1
    #pragma unroll
    for (int c = 0; c < 4; ++c) acc[c] += __shfl_xor(acc[c], 32);
    if (lane < 32) red4[wv * 32 + lane] = acc;
    __syncthreads();
    if (t < TS) {
        const float* red = (const float*)red4;
        float tot = 0.0f;
        #pragma unroll
        for (int w = 0; w < 16; ++w) tot += red[w * TS + t];
        const float q1 = q0s[t] + (mrow[t] ? tot : 0.0f);
        g1s[t] = exp2f(clampe(-q1));
    }
    __syncthreads();

    // ---- pass 2: u2 via 1 rcp/score, pure register math ----
    acc[0] = acc[1] = acc[2] = acc[3] = 0.0f;
    #pragma unroll
    for (int r = 0; r < 4; ++r) {
        const int i = rg + 32 * r;
        const bool live = (mrow[i] != 0) && (i != j);
        if (live) {
            const float p1 = p1s[i], r1 = r1s[i], g1 = g1s[i];
            const f4v fs = __builtin_convertvector(Fs[r], f4v);
            const f4v fc = __builtin_convertvector(Fc[r], f4v);
            const f4v fg = __builtin_convertvector(Fg[r], f4v);
            #pragma unroll
            for (int c = 0; c < 4; ++c) {
                float p, us, uc, ug;
                us = (p1 + fs[c]) * r1;  p = us * g1;  us = (p + fs[c]) * rcpf(1.0f + p);
                uc = (p1 + fc[c]) * r1;  p = uc * g1;  uc = (p + fc[c]) * rcpf(1.0f + p);
                ug = (p1 + fg[c]) * r1;  p = ug * g1;  ug = (p + fg[c]) * rcpf(1.0f + p);
                const float l = __log2f(us * uc * ug);
                if (i != k0 + c) acc[c] += l;
            }
        }
    }

    // reduce -> q2 -> g2
    #pragma unroll
    for (int c = 0; c < 4; ++c) acc[c] += __shfl_xor(acc[c], 32);
    if (lane < 32) red4[wv * 32 + lane] = acc;
    __syncthreads();
    if (t < TS) {
        const float* red = (const float*)red4;
        float tot = 0.0f;
        #pragma unroll
        for (int w = 0; w < 16; ++w) tot += red[w * TS + t];
        const float q2 = q0s[t] + (mrow[t] ? tot : 0.0f);
        g2s[t] = exp2f(clampe(-q2));
    }
    __syncthreads();

    // ---- pass 3: u3 via 2 rcp/score ----
    acc[0] = acc[1] = acc[2] = acc[3] = 0.0f;
    #pragma unroll
    for (int r = 0; r < 4; ++r) {
        const int i = rg + 32 * r;
        const bool live = (mrow[i] != 0) && (i != j);
        if (live) {
            const float p1 = p1s[i], r1 = r1s[i], g1 = g1s[i], g2 = g2s[i];
            const f4v fs = __builtin_convertvector(Fs[r], f4v);
            const f4v fc = __builtin_convertvector(Fc[r], f4v);
            const f4v fg = __builtin_convertvector(Fg[r], f4v);
            #pragma unroll
            for (int c = 0; c < 4; ++c) {
                float p, us, uc, ug;
                us = (p1 + fs[c]) * r1;  p = us * g1;  us = (p + fs[c]) * rcpf(1.0f + p);
                p = us * g2;  us = (p + fs[c]) * rcpf(1.0f + p);
                uc = (p1 + fc[c]) * r1;  p = uc * g1;  uc = (p + fc[c]) * rcpf(1.0f + p);
                p = uc * g2;  uc = (p + fc[c]) * rcpf(1.0f + p);
                ug = (p1 + fg[c]) * r1;  p = ug * g1;  ug = (p + fg[c]) * rcpf(1.0f + p);
                p = ug * g2;  ug = (p + fg[c]) * rcpf(1.0f + p);
                const float l = __log2f(us * uc * ug);
                if (i != k0 + c) acc[c] += l;
            }
        }
    }

    // reduce -> q3 -> output
    #pragma unroll
    for (int c = 0; c < 4; ++c) acc[c] += __shfl_xor(acc[c], 32);
    if (lane < 32) red4[wv * 32 + lane] = acc;
    __syncthreads();
    if (t < TS) {
        const float* red = (const float*)red4;
        float tot = 0.0f;
        #pragma unroll
        for (int w = 0; w < 16; ++w) tot += red[w * TS + t];
        const float q3 = q0s[t] + (mrow[t] ? tot : 0.0f);
        outp[(b * TS + t) * TS + j] = 1.0f / (1.0f + exp2f(clampe(-q3)));
    }
}

extern "C" void kernel_launch(void* const* d_in, const int* in_sizes, int n_in,
                              void* d_out, int out_size, void* d_ws, size_t ws_size,
                              hipStream_t stream) {
    const float* s_edge = (const float*)d_in[0];
    const f4v*   sib4   = (const f4v*)d_in[1];
    const f4v*   cop4   = (const f4v*)d_in[2];
    const f4v*   grd4   = (const f4v*)d_in[3];
    const void*  mask   = d_in[4];
    float* out = (float*)d_out;

    const int Bn = in_sizes[0] / (TS * TS);   // batch
    const int nMask = in_sizes[4];            // B*S*S elements

    int* flags = (int*)d_ws;

    flags_init<<<1, 1, 0, stream>>>(flags);
    mask_detect<<<64, 256, 0, stream>>>((const unsigned char*)mask, nMask, flags);
    lbp_fused<<<Bn * TS, 1024, 0, stream>>>(s_edge, sib4, cop4, grd4, mask, flags, out);
}

// Round 11
// 84.239 us; speedup vs baseline: 2.9645x; 1.0154x over previous
//
#include <hip/hip_runtime.h>

// LBP for semantic dependency parsing — label-difference form, all 3
// iterations fused, u-SPACE chain (u = 2^D), fp16 F payload.
// Staging via global_load_lds DMA (zero staging VGPRs): r10 showed the
// register allocator silently serializes register-staged loads (~5 in
// flight -> 1.3 TB/s); DMA-to-LDS decouples MLP from the register file.
//
//   F[b,i,j,k] = 2^(log2e*s) = e^s                (only use of the scores)
//   u_1 = (p1 + F)*r1,          p1 = 2^(-q0[i]), r1 = 1/(1+p1)
//   u_t = (p + F)/(1 + p),      p = u_{t-1} * 2^(-q_{t-1}[i])
//   q_t[k] = q0[k] + mask[k] * sum_i log2(u_s*u_c*u_g)[i,k]
//                               * mask[i]*(i!=j)*(i!=k)
//   out[b,k,j] = 1/(1+2^(-q_3[k]))
//
// Geometry: block (b,j), 1024 thr, thread = (kq=t&31 -> 4 k's, rg=t>>5 ->
// rows rg+32r). Wave wv owns rows {2wv,2wv+1} (+32r): it DMAs those rows
// (3 tensors, 3x1KB instrs, per-lane global addr, linear LDS dest), waits
// its own vmcnt(0) — NO block barriers during staging — and consumes via
// conflict-free ds_read_b128. F kept as fp16 regs (24 VGPR, precision
// proven r7-r10: absmax 0.0078 vs thr 0.02); passes 2-3 pure register math.

#define TS 128

typedef float    f4v __attribute__((ext_vector_type(4)));
typedef _Float16 h4v __attribute__((ext_vector_type(4)));

constexpr float LOG2E = 1.4426950408889634f;

__device__ __forceinline__ float rcpf(float x)   { return __builtin_amdgcn_rcpf(x); }
__device__ __forceinline__ float clampe(float e) { return fminf(fmaxf(e, -126.0f), 60.0f); }

__device__ __forceinline__ void gload_lds16(const float* g, float* l) {
    __builtin_amdgcn_global_load_lds((const __attribute__((address_space(1))) void*)g,
                                     (__attribute__((address_space(3))) void*)l,
                                     16, 0, 0);
}

// ---- single-block mask format probe: f[0]!=0 byte mask, f[1]!=0 f32, else i32
__global__ void mask_probe(const unsigned char* __restrict__ m, int n, int* __restrict__ f) {
    __shared__ int s1, s23;
    if (threadIdx.x == 0) { s1 = 0; s23 = 0; }
    __syncthreads();
    unsigned a1 = 0, a23 = 0;
    const int n16 = n >> 4;
    const uint4* m4 = (const uint4*)m;
    for (int i = threadIdx.x; i < n16; i += 1024) {
        const uint4 v = m4[i];
        const unsigned o = v.x | v.y | v.z | v.w;
        a1  |= o & 0x0000FF00u;
        a23 |= o & 0xFFFF0000u;
    }
    for (int i = (n16 << 4) + threadIdx.x; i < n; i += 1024) {  // tail bytes
        const unsigned char b = m[i];
        const int r = i & 3;
        if (r == 1) a1 |= b;
        if (r >= 2) a23 |= b;
    }
    if (__any(a1 != 0)  && (threadIdx.x & 63) == 0) atomicOr(&s1, 1);
    if (__any(a23 != 0) && (threadIdx.x & 63) == 0) atomicOr(&s23, 1);
    __syncthreads();
    if (threadIdx.x == 0) { f[0] = s1; f[1] = s23; }
}

__global__ __launch_bounds__(1024)
void lbp_fused(const float* __restrict__ s_edge,
               const float* __restrict__ sib,
               const float* __restrict__ cop,
               const float* __restrict__ grd,
               const void* __restrict__ mask,
               const int* __restrict__ flags,
               float* __restrict__ outp)
{
    __shared__ float ldsS[16][2][TS];   // 16 KB: [wave][rowslot][k]
    __shared__ float ldsC[16][2][TS];
    __shared__ float ldsG[16][2][TS];
    __shared__ f4v red4[16 * 32];       // 8 KB: [wave][k-quad]
    __shared__ float q0s[TS], p1s[TS], r1s[TS], g1s[TS], g2s[TS];
    __shared__ unsigned char mrow[TS];

    const int bj = blockIdx.x;
    const int b  = bj >> 7;
    const int j  = bj & (TS - 1);
    const int t  = threadIdx.x;
    const int kq = t & 31;              // k = 4*kq .. 4*kq+3
    const int rg = t >> 5;              // 0..31: rows rg, rg+32, rg+64, rg+96
    const int k0 = kq * 4;
    const int lane = t & 63;
    const int wv = t >> 6;              // wave 0..15; owns rows {2wv, 2wv+1}(+32r)
    const int sl = rg & 1;              // this thread's row slot in its wave

    // ---- per-column prologue ----
    if (t < TS) {
        const int i = t;
        const int idx = (b * TS + i) * TS + j;
        const float q0 = LOG2E * s_edge[idx];
        q0s[i] = q0;
        const int f1 = flags[0], f23 = flags[1];
        unsigned char mv;
        if (f1)       mv = ((const unsigned char*)mask)[idx] != 0;
        else if (f23) mv = ((const float*)mask)[idx] != 0.0f;
        else          mv = ((const int*)mask)[idx]   != 0;
        mrow[i] = mv;
        const float p1 = exp2f(clampe(-q0));
        p1s[i] = p1;
        r1s[i] = rcpf(1.0f + p1);
    }
    __syncthreads();

    // per-lane global element offset for this wave's DMA: row 2wv+(lane>>5),
    // k = 4*(lane&31); LDS dest is linear (lane*16B) matching [2][128] layout
    const size_t gcol = ((size_t)(b * TS) * TS + j) * TS;
    const size_t gLane = gcol + (size_t)(2 * wv + (lane >> 5)) * (TS * TS) + 4 * (lane & 31);

    // ---- stage (DMA, barrier-free) + pass 1: F = e^s (fp16), u1, acc ----
    h4v Fs[4], Fc[4], Fg[4];
    f4v acc = {0.0f, 0.0f, 0.0f, 0.0f};
    #pragma unroll
    for (int r = 0; r < 4; ++r) {
        const size_t g = gLane + (size_t)(32 * r) * (TS * TS);
        gload_lds16(sib + g, &ldsS[wv][0][0]);
        gload_lds16(cop + g, &ldsC[wv][0][0]);
        gload_lds16(grd + g, &ldsG[wv][0][0]);
        asm volatile("s_waitcnt vmcnt(0)" ::: "memory");   // this wave's DMA only

        const int i = rg + 32 * r;
        const f4v vs = *(const f4v*)&ldsS[wv][sl][k0];
        const f4v vc = *(const f4v*)&ldsC[wv][sl][k0];
        const f4v vg = *(const f4v*)&ldsG[wv][sl][k0];

        f4v fs, fc, fg;
        #pragma unroll
        for (int c = 0; c < 4; ++c) {
            fs[c] = exp2f(LOG2E * vs[c]);
            fc[c] = exp2f(LOG2E * vc[c]);
            fg[c] = exp2f(LOG2E * vg[c]);
        }
        Fs[r] = __builtin_convertvector(fs, h4v);
        Fc[r] = __builtin_convertvector(fc, h4v);
        Fg[r] = __builtin_convertvector(fg, h4v);
        const bool live = (mrow[i] != 0) && (i != j);
        const float p1 = p1s[i], r1 = r1s[i];
        #pragma unroll
        for (int c = 0; c < 4; ++c) {
            const float us = (p1 + fs[c]) * r1;
            const float uc = (p1 + fc[c]) * r1;
            const float ug = (p1 + fg[c]) * r1;
            const float l  = __log2f(us * uc * ug);
            if (live && (i != k0 + c)) acc[c] += l;
        }
        // drain ds_reads before next iteration's DMA may overwrite the slot
        asm volatile("s_waitcnt lgkmcnt(0)" ::: "memory");
    }

    // reduce -> q1 -> g1
    #pragma unroll
    for (int c = 0; c < 4; ++c) acc[c] += __shfl_xor(acc[c], 32);
    if (lane < 32) red4[wv * 32 + lane] = acc;
    __syncthreads();
    if (t < TS) {
        const float* red = (const float*)red4;
        float tot = 0.0f;
        #pragma unroll
        for (int w = 0; w < 16; ++w) tot += red[w * TS + t];
        const float q1 = q0s[t] + (mrow[t] ? tot : 0.0f);
        g1s[t] = exp2f(clampe(-q1));
    }
    __syncthreads();

    // ---- pass 2: u2 via 1 rcp/score, pure register math ----
    acc[0] = acc[1] = acc[2] = acc[3] = 0.0f;
    #pragma unroll
    for (int r = 0; r < 4; ++r) {
        const int i = rg + 32 * r;
        const bool live = (mrow[i] != 0) && (i != j);
        if (live) {
            const float p1 = p1s[i], r1 = r1s[i], g1 = g1s[i];
            const f4v fs = __builtin_convertvector(Fs[r], f4v);
            const f4v fc = __builtin_convertvector(Fc[r], f4v);
            const f4v fg = __builtin_convertvector(Fg[r], f4v);
            #pragma unroll
            for (int c = 0; c < 4; ++c) {
                float p, us, uc, ug;
                us = (p1 + fs[c]) * r1;  p = us * g1;  us = (p + fs[c]) * rcpf(1.0f + p);
                uc = (p1 + fc[c]) * r1;  p = uc * g1;  uc = (p + fc[c]) * rcpf(1.0f + p);
                ug = (p1 + fg[c]) * r1;  p = ug * g1;  ug = (p + fg[c]) * rcpf(1.0f + p);
                const float l = __log2f(us * uc * ug);
                if (i != k0 + c) acc[c] += l;
            }
        }
    }

    // reduce -> q2 -> g2
    #pragma unroll
    for (int c = 0; c < 4; ++c) acc[c] += __shfl_xor(acc[c], 32);
    if (lane < 32) red4[wv * 32 + lane] = acc;
    __syncthreads();
    if (t < TS) {
        const float* red = (const float*)red4;
        float tot = 0.0f;
        #pragma unroll
        for (int w = 0; w < 16; ++w) tot += red[w * TS + t];
        const float q2 = q0s[t] + (mrow[t] ? tot : 0.0f);
        g2s[t] = exp2f(clampe(-q2));
    }
    __syncthreads();

    // ---- pass 3: u3 via 2 rcp/score ----
    acc[0] = acc[1] = acc[2] = acc[3] = 0.0f;
    #pragma unroll
    for (int r = 0; r < 4; ++r) {
        const int i = rg + 32 * r;
        const bool live = (mrow[i] != 0) && (i != j);
        if (live) {
            const float p1 = p1s[i], r1 = r1s[i], g1 = g1s[i], g2 = g2s[i];
            const f4v fs = __builtin_convertvector(Fs[r], f4v);
            const f4v fc = __builtin_convertvector(Fc[r], f4v);
            const f4v fg = __builtin_convertvector(Fg[r], f4v);
            #pragma unroll
            for (int c = 0; c < 4; ++c) {
                float p, us, uc, ug;
                us = (p1 + fs[c]) * r1;  p = us * g1;  us = (p + fs[c]) * rcpf(1.0f + p);
                p = us * g2;  us = (p + fs[c]) * rcpf(1.0f + p);
                uc = (p1 + fc[c]) * r1;  p = uc * g1;  uc = (p + fc[c]) * rcpf(1.0f + p);
                p = uc * g2;  uc = (p + fc[c]) * rcpf(1.0f + p);
                ug = (p1 + fg[c]) * r1;  p = ug * g1;  ug = (p + fg[c]) * rcpf(1.0f + p);
                p = ug * g2;  ug = (p + fg[c]) * rcpf(1.0f + p);
                const float l = __log2f(us * uc * ug);
                if (i != k0 + c) acc[c] += l;
            }
        }
    }

    // reduce -> q3 -> output
    #pragma unroll
    for (int c = 0; c < 4; ++c) acc[c] += __shfl_xor(acc[c], 32);
    if (lane < 32) red4[wv * 32 + lane] = acc;
    __syncthreads();
    if (t < TS) {
        const float* red = (const float*)red4;
        float tot = 0.0f;
        #pragma unroll
        for (int w = 0; w < 16; ++w) tot += red[w * TS + t];
        const float q3 = q0s[t] + (mrow[t] ? tot : 0.0f);
        outp[(b * TS + t) * TS + j] = 1.0f / (1.0f + exp2f(clampe(-q3)));
    }
}

extern "C" void kernel_launch(void* const* d_in, const int* in_sizes, int n_in,
                              void* d_out, int out_size, void* d_ws, size_t ws_size,
                              hipStream_t stream) {
    const float* s_edge = (const float*)d_in[0];
    const float* sib    = (const float*)d_in[1];
    const float* cop    = (const float*)d_in[2];
    const float* grd    = (const float*)d_in[3];
    const void*  mask   = d_in[4];
    float* out = (float*)d_out;

    const int Bn = in_sizes[0] / (TS * TS);   // batch
    const int nMask = in_sizes[4];            // B*S*S elements

    int* flags = (int*)d_ws;

    mask_probe<<<1, 1024, 0, stream>>>((const unsigned char*)mask, nMask, flags);
    lbp_fused<<<Bn * TS, 1024, 0, stream>>>(s_edge, sib, cop, grd, mask, flags, out);
}

// Round 12
// 73.511 us; speedup vs baseline: 3.3971x; 1.1459x over previous
//
#include <hip/hip_runtime.h>

// LBP for semantic dependency parsing — label-difference form, all 3
// iterations fused, u-SPACE chain (u = 2^D), fp16 F + fp16 u2 payload,
// DOUBLE-BUFFERED global_load_lds staging (counted vmcnt, never 0 in the
// steady state — r11's vmcnt(0)-per-tile serialized the pipeline).
//
//   F[b,i,j,k] = 2^(log2e*s) = e^s                (only use of the scores)
//   u_1 = (p1 + F)*r1,          p1 = 2^(-q0[i]), r1 = 1/(1+p1)
//   u_t = (p + F)/(1 + p),      p = u_{t-1} * 2^(-q_{t-1}[i])
//   q_t[k] = q0[k] + mask[k] * sum_i log2(u_s*u_c*u_g)[i,k]
//                               * mask[i]*(i!=j)*(i!=k)
//   out[b,k,j] = 1/(1+2^(-q_3[k]))
//
// Geometry: block (b,j), 1024 thr; thread = (kq=t&31 -> 4 k's, rg=t>>5 ->
// rows rg+32r). Wave wv owns rows {2wv,2wv+1}(+32r): DMAs them into its
// private double-buffered LDS slot (3 tensors x 1 KB per tile), waits a
// COUNTED vmcnt(3) so the next tile stays in flight, consumes via
// conflict-free ds_read_b128. Occupancy is empirically 1 block/CU (44%)
// for every 1024-thr variant -> __launch_bounds__(1024,4) declares exactly
// that, unlocking a 128-VGPR budget: F (24) + u2 (24) fp16 payload fits,
// so pass 3 needs only 1 rcp/score instead of re-running the chain.

#define TS 128

typedef float    f4v __attribute__((ext_vector_type(4)));
typedef _Float16 h4v __attribute__((ext_vector_type(4)));

constexpr float LOG2E = 1.4426950408889634f;

__device__ __forceinline__ float rcpf(float x)   { return __builtin_amdgcn_rcpf(x); }
__device__ __forceinline__ float clampe(float e) { return fminf(fmaxf(e, -126.0f), 60.0f); }

__device__ __forceinline__ void gload_lds16(const float* g, float* l) {
    __builtin_amdgcn_global_load_lds((const __attribute__((address_space(1))) void*)g,
                                     (__attribute__((address_space(3))) void*)l,
                                     16, 0, 0);
}

// ---- single-block mask format probe: f[0]!=0 byte mask, f[1]!=0 f32, else i32
__global__ void mask_probe(const unsigned char* __restrict__ m, int n, int* __restrict__ f) {
    __shared__ int s1, s23;
    if (threadIdx.x == 0) { s1 = 0; s23 = 0; }
    __syncthreads();
    unsigned a1 = 0, a23 = 0;
    const int n16 = n >> 4;
    const uint4* m4 = (const uint4*)m;
    for (int i = threadIdx.x; i < n16; i += 1024) {
        const uint4 v = m4[i];
        const unsigned o = v.x | v.y | v.z | v.w;
        a1  |= o & 0x0000FF00u;
        a23 |= o & 0xFFFF0000u;
    }
    for (int i = (n16 << 4) + threadIdx.x; i < n; i += 1024) {  // tail bytes
        const unsigned char b = m[i];
        const int r = i & 3;
        if (r == 1) a1 |= b;
        if (r >= 2) a23 |= b;
    }
    if (__any(a1 != 0)  && (threadIdx.x & 63) == 0) atomicOr(&s1, 1);
    if (__any(a23 != 0) && (threadIdx.x & 63) == 0) atomicOr(&s23, 1);
    __syncthreads();
    if (threadIdx.x == 0) { f[0] = s1; f[1] = s23; }
}

__global__ __launch_bounds__(1024, 4)
void lbp_fused(const float* __restrict__ s_edge,
               const float* __restrict__ sib,
               const float* __restrict__ cop,
               const float* __restrict__ grd,
               const void* __restrict__ mask,
               const int* __restrict__ flags,
               float* __restrict__ outp)
{
    __shared__ float ldsS[16][2][2][TS];   // 32 KB: [wave][slot][rowpair][k]
    __shared__ float ldsC[16][2][2][TS];
    __shared__ float ldsG[16][2][2][TS];
    __shared__ f4v red4[16 * 32];          // 8 KB: [wave][k-quad]
    __shared__ float q0s[TS], p1s[TS], r1s[TS], g1s[TS], g2s[TS];
    __shared__ unsigned char mrow[TS];

    const int bj = blockIdx.x;
    const int b  = bj >> 7;
    const int j  = bj & (TS - 1);
    const int t  = threadIdx.x;
    const int kq = t & 31;              // k = 4*kq .. 4*kq+3
    const int rg = t >> 5;              // 0..31: rows rg, rg+32, rg+64, rg+96
    const int k0 = kq * 4;
    const int lane = t & 63;
    const int wv = t >> 6;              // wave 0..15; owns rows {2wv,2wv+1}(+32r)
    const int sl = rg & 1;              // row slot within the wave's tile

    // ---- per-column prologue ----
    if (t < TS) {
        const int i = t;
        const int idx = (b * TS + i) * TS + j;
        const float q0 = LOG2E * s_edge[idx];
        q0s[i] = q0;
        const int f1 = flags[0], f23 = flags[1];
        unsigned char mv;
        if (f1)       mv = ((const unsigned char*)mask)[idx] != 0;
        else if (f23) mv = ((const float*)mask)[idx] != 0.0f;
        else          mv = ((const int*)mask)[idx]   != 0;
        mrow[i] = mv;
        const float p1 = exp2f(clampe(-q0));
        p1s[i] = p1;
        r1s[i] = rcpf(1.0f + p1);
    }
    __syncthreads();

    // per-lane global element offset: row 2wv+(lane>>5), k = 4*(lane&31);
    // LDS dest is linear (lane*16B), matching the [2][TS] tile layout
    const size_t gcol = ((size_t)(b * TS) * TS + j) * TS;
    const size_t gLane = gcol + (size_t)(2 * wv + (lane >> 5)) * (TS * TS) + 4 * (lane & 31);

    // ---- prologue DMA: tile 0 into slot 0 ----
    gload_lds16(sib + gLane, &ldsS[wv][0][0][0]);
    gload_lds16(cop + gLane, &ldsC[wv][0][0][0]);
    gload_lds16(grd + gLane, &ldsG[wv][0][0][0]);

    // ---- stage (double-buffered DMA, barrier-free) + pass 1 ----
    h4v Fs[4], Fc[4], Fg[4];
    f4v acc = {0.0f, 0.0f, 0.0f, 0.0f};
    #pragma unroll
    for (int r = 0; r < 4; ++r) {
        if (r < 3) {
            // prior ds_reads of the slot we are about to overwrite are done
            asm volatile("s_waitcnt lgkmcnt(0)" ::: "memory");
            const size_t g = gLane + (size_t)(32 * (r + 1)) * (TS * TS);
            const int s = (r + 1) & 1;
            gload_lds16(sib + g, &ldsS[wv][s][0][0]);
            gload_lds16(cop + g, &ldsC[wv][s][0][0]);
            gload_lds16(grd + g, &ldsG[wv][s][0][0]);
            asm volatile("s_waitcnt vmcnt(3)" ::: "memory");   // tile r landed; r+1 in flight
        } else {
            asm volatile("s_waitcnt vmcnt(0)" ::: "memory");
        }
        const int s0 = r & 1;
        const f4v vs = *(const f4v*)&ldsS[wv][s0][sl][k0];
        const f4v vc = *(const f4v*)&ldsC[wv][s0][sl][k0];
        const f4v vg = *(const f4v*)&ldsG[wv][s0][sl][k0];

        const int i = rg + 32 * r;
        f4v fs, fc, fg;
        #pragma unroll
        for (int c = 0; c < 4; ++c) {
            fs[c] = exp2f(LOG2E * vs[c]);
            fc[c] = exp2f(LOG2E * vc[c]);
            fg[c] = exp2f(LOG2E * vg[c]);
        }
        Fs[r] = __builtin_convertvector(fs, h4v);
        Fc[r] = __builtin_convertvector(fc, h4v);
        Fg[r] = __builtin_convertvector(fg, h4v);
        const bool live = (mrow[i] != 0) && (i != j);
        const float p1 = p1s[i], r1 = r1s[i];
        #pragma unroll
        for (int c = 0; c < 4; ++c) {
            const float us = (p1 + fs[c]) * r1;
            const float uc = (p1 + fc[c]) * r1;
            const float ug = (p1 + fg[c]) * r1;
            const float l  = __log2f(us * uc * ug);
            if (live && (i != k0 + c)) acc[c] += l;
        }
    }

    // reduce -> q1 -> g1
    #pragma unroll
    for (int c = 0; c < 4; ++c) acc[c] += __shfl_xor(acc[c], 32);
    if (lane < 32) red4[wv * 32 + lane] = acc;
    __syncthreads();
    if (t < TS) {
        const float* red = (const float*)red4;
        float tot = 0.0f;
        #pragma unroll
        for (int w = 0; w < 16; ++w) tot += red[w * TS + t];
        const float q1 = q0s[t] + (mrow[t] ? tot : 0.0f);
        g1s[t] = exp2f(clampe(-q1));
    }
    __syncthreads();

    // ---- pass 2: u2 via 1 rcp/score; keep u2 in fp16 regs for pass 3 ----
    h4v U2s[4], U2c[4], U2g[4];
    acc[0] = acc[1] = acc[2] = acc[3] = 0.0f;
    #pragma unroll
    for (int r = 0; r < 4; ++r) {
        const int i = rg + 32 * r;
        const bool live = (mrow[i] != 0) && (i != j);
        const float p1 = p1s[i], r1 = r1s[i], g1 = g1s[i];
        const f4v fs = __builtin_convertvector(Fs[r], f4v);
        const f4v fc = __builtin_convertvector(Fc[r], f4v);
        const f4v fg = __builtin_convertvector(Fg[r], f4v);
        f4v u2s, u2c, u2g;
        #pragma unroll
        for (int c = 0; c < 4; ++c) {
            float p, us, uc, ug;
            us = (p1 + fs[c]) * r1;  p = us * g1;  us = (p + fs[c]) * rcpf(1.0f + p);
            uc = (p1 + fc[c]) * r1;  p = uc * g1;  uc = (p + fc[c]) * rcpf(1.0f + p);
            ug = (p1 + fg[c]) * r1;  p = ug * g1;  ug = (p + fg[c]) * rcpf(1.0f + p);
            u2s[c] = us; u2c[c] = uc; u2g[c] = ug;
            const float l = __log2f(us * uc * ug);
            if (live && (i != k0 + c)) acc[c] += l;
        }
        U2s[r] = __builtin_convertvector(u2s, h4v);
        U2c[r] = __builtin_convertvector(u2c, h4v);
        U2g[r] = __builtin_convertvector(u2g, h4v);
    }

    // reduce -> q2 -> g2
    #pragma unroll
    for (int c = 0; c < 4; ++c) acc[c] += __shfl_xor(acc[c], 32);
    if (lane < 32) red4[wv * 32 + lane] = acc;
    __syncthreads();
    if (t < TS) {
        const float* red = (const float*)red4;
        float tot = 0.0f;
        #pragma unroll
        for (int w = 0; w < 16; ++w) tot += red[w * TS + t];
        const float q2 = q0s[t] + (mrow[t] ? tot : 0.0f);
        g2s[t] = exp2f(clampe(-q2));
    }
    __syncthreads();

    // ---- pass 3: u3 from stored u2 — 1 rcp/score ----
    acc[0] = acc[1] = acc[2] = acc[3] = 0.0f;
    #pragma unroll
    for (int r = 0; r < 4; ++r) {
        const int i = rg + 32 * r;
        const bool live = (mrow[i] != 0) && (i != j);
        if (live) {
            const float g2 = g2s[i];
            const f4v fs = __builtin_convertvector(Fs[r], f4v);
            const f4v fc = __builtin_convertvector(Fc[r], f4v);
            const f4v fg = __builtin_convertvector(Fg[r], f4v);
            const f4v u2s = __builtin_convertvector(U2s[r], f4v);
            const f4v u2c = __builtin_convertvector(U2c[r], f4v);
            const f4v u2g = __builtin_convertvector(U2g[r], f4v);
            #pragma unroll
            for (int c = 0; c < 4; ++c) {
                float p, us, uc, ug;
                p = u2s[c] * g2;  us = (p + fs[c]) * rcpf(1.0f + p);
                p = u2c[c] * g2;  uc = (p + fc[c]) * rcpf(1.0f + p);
                p = u2g[c] * g2;  ug = (p + fg[c]) * rcpf(1.0f + p);
                const float l = __log2f(us * uc * ug);
                if (i != k0 + c) acc[c] += l;
            }
        }
    }

    // reduce -> q3 -> output
    #pragma unroll
    for (int c = 0; c < 4; ++c) acc[c] += __shfl_xor(acc[c], 32);
    if (lane < 32) red4[wv * 32 + lane] = acc;
    __syncthreads();
    if (t < TS) {
        const float* red = (const float*)red4;
        float tot = 0.0f;
        #pragma unroll
        for (int w = 0; w < 16; ++w) tot += red[w * TS + t];
        const float q3 = q0s[t] + (mrow[t] ? tot : 0.0f);
        outp[(b * TS + t) * TS + j] = 1.0f / (1.0f + exp2f(clampe(-q3)));
    }
}

extern "C" void kernel_launch(void* const* d_in, const int* in_sizes, int n_in,
                              void* d_out, int out_size, void* d_ws, size_t ws_size,
                              hipStream_t stream) {
    const float* s_edge = (const float*)d_in[0];
    const float* sib    = (const float*)d_in[1];
    const float* cop    = (const float*)d_in[2];
    const float* grd    = (const float*)d_in[3];
    const void*  mask   = d_in[4];
    float* out = (float*)d_out;

    const int Bn = in_sizes[0] / (TS * TS);   // batch
    const int nMask = in_sizes[4];            // B*S*S elements

    int* flags = (int*)d_ws;

    mask_probe<<<1, 1024, 0, stream>>>((const unsigned char*)mask, nMask, flags);
    lbp_fused<<<Bn * TS, 1024, 0, stream>>>(s_edge, sib, cop, grd, mask, flags, out);
}